// Round 24
// baseline (269.216 us; speedup 1.0000x reference)
//
#include <hip/hip_runtime.h>

typedef __bf16 bfv8 __attribute__((ext_vector_type(8)));
typedef float f32x4 __attribute__((ext_vector_type(4)));
typedef short s16x8 __attribute__((ext_vector_type(8)));
typedef unsigned int u32;
typedef unsigned int u32x4 __attribute__((ext_vector_type(4)));

#define MFMA16(a,b,c) __builtin_amdgcn_mfma_f32_16x16x32_bf16((a),(b),(c),0,0,0)

__device__ __forceinline__ u32 pk2(float a, float b){
  u32 r; asm("v_cvt_pk_bf16_f32 %0, %1, %2" : "=v"(r) : "v"(a), "v"(b)); return r;
}
__device__ __forceinline__ bfv8 cvt8s(const float* p, float s){
  u32x4 r;
  #pragma unroll
  for (int j=0;j<4;++j) r[j] = pk2(p[2*j]*s, p[2*j+1]*s);
  return *(bfv8*)&r;
}
// async global->LDS, 16B/lane (used by proj only)
__device__ __forceinline__ void glds16(const short* g, short* l){
  __builtin_amdgcn_global_load_lds(
      (const __attribute__((address_space(1))) u32*)g,
      (__attribute__((address_space(3))) u32*)l, 16, 0, 0);
}

// Fused prep (UNSWIZZLED layouts for direct-global fragment reads):
//  [0,2048):    K fp32 -> Kt tiles [bh][kt][r=64][d=64] bf16 (plain per-head tiles)
//  [2048,3072): V fp32 -> Vt tiles [bh][kt][d=64][slot=64] bf16 (V^T, sigma64 slots,
//               masked V-rows zeroed)
//  [3072,3584): Wo fp32 -> bf16
//  [3584,3600): key_mask -> sigma64 bf16 0/1 frags kms[b][kt][64]
__global__ __launch_bounds__(256) void prep(const float* __restrict__ K, const float* __restrict__ V,
                                            const float* __restrict__ Wo, const int* __restrict__ km,
                                            short* __restrict__ Kt, short* __restrict__ Vt,
                                            short* __restrict__ Wb, short* __restrict__ kms){
  __shared__ short tl[64][65];
  const int bid = blockIdx.x, tid = threadIdx.x;
  if (bid < 2048){
    int idx = bid*256 + tid;
    int cs = idx & 7, r = (idx >> 3) & 63, kt = (idx >> 9) & 31, bh = idx >> 14;
    int b = bh >> 4, h = bh & 15;
    const float* src = K + ((size_t)(b*2048 + kt*64 + r))*1024 + h*64 + cs*8;
    float4 a = ((const float4*)src)[0], bb = ((const float4*)src)[1];
    u32x4 o;
    o[0]=pk2(a.x,a.y); o[1]=pk2(a.z,a.w); o[2]=pk2(bb.x,bb.y); o[3]=pk2(bb.z,bb.w);
    ((u32x4*)Kt)[idx] = o;
  } else if (bid < 3072){
    int vb = bid - 2048;
    int kt = vb & 31, bh = vb >> 5;
    int b = bh >> 4, h = bh & 15;
    {
      int s = tid >> 2, d0 = (tid & 3) * 16;
      float kmv = (km[b*2048 + kt*64 + s] != 0) ? 1.0f : 0.0f;   // fold mask into V
      const float* src = V + ((size_t)(b*2048 + kt*64 + s))*1024 + h*64 + d0;
      #pragma unroll
      for (int j = 0; j < 4; ++j){
        float4 v = ((const float4*)src)[j];
        tl[d0+4*j+0][s] = (short)(pk2(v.x*kmv, 0.f) & 0xffff);
        tl[d0+4*j+1][s] = (short)(pk2(v.y*kmv, 0.f) & 0xffff);
        tl[d0+4*j+2][s] = (short)(pk2(v.z*kmv, 0.f) & 0xffff);
        tl[d0+4*j+3][s] = (short)(pk2(v.w*kmv, 0.f) & 0xffff);
      }
    }
    __syncthreads();
    {
      int r = tid >> 2, cp = (tid & 3) * 2;
      short* dst = Vt + (((size_t)(bh*32 + kt)*64 + r) << 6);
      #pragma unroll
      for (int q = 0; q < 2; ++q){
        int cs = cp + q;
        s16x8 o;
        #pragma unroll
        for (int j = 0; j < 8; ++j){
          int s = cs*8 + j;                   // logical slot 0..63
          int sg = s >> 2, rr = s & 3;
          int t = (sg >> 3)*2 + (sg & 1);
          int a = (sg >> 1) & 3;
          int kap = t*16 + a*4 + rr;          // sigma64^-1(slot)
          o[j] = tl[r][kap];
        }
        *(s16x8*)(dst + cs*8) = o;
      }
    }
  } else if (bid < 3584){
    int i = (bid - 3072)*256 + tid;
    const float* p = Wo + (size_t)i*8;
    u32x4 o;
    o[0]=pk2(p[0],p[1]); o[1]=pk2(p[2],p[3]); o[2]=pk2(p[4],p[5]); o[3]=pk2(p[6],p[7]);
    ((u32x4*)Wb)[i] = o;
  } else {
    int i = (bid - 3584)*256 + tid;   // 0..4095: [b][kt][slot]
    if (i < 4096){
      int bb = i >> 11, kt = (i >> 6) & 31, s = i & 63;
      int rr = s & 3, a = (s >> 3) & 3, t = ((s >> 5) & 1)*2 + ((s >> 2) & 1);
      int key = t*16 + a*4 + rr;     // sigma64^-1(slot)
      kms[i] = (km[bb*2048 + kt*64 + key] != 0) ? (short)0x3F80 : (short)0;
    }
  }
}

// Flash attention, LDS-FREE / BARRIER-FREE: all fragments read directly from
// global (K,V,kms are L1/L2-resident per XCD). 4 waves x 16 q-rows, grid 1024.
// Fixed-base softmax, mask-in-V, l via mask-frag MFMA. No sync hazards exist.
__global__ __launch_bounds__(256) void attn15(const short* __restrict__ Kt, const short* __restrict__ Vt,
                                              const float* __restrict__ Qf, const short* __restrict__ kms,
                                              const int* __restrict__ qmask, short* __restrict__ X){
  const int wid = blockIdx.x;
  const int bh = (wid & 7)*4 + (wid >> 8);       // xcd*4 + head-group
  const int qt = (wid >> 3) & 31;                // 32 q-tiles of 64 rows
  const int b = bh >> 4, h = bh & 15;
  const int tid = threadIdx.x;
  const int w = tid >> 6, lane = tid & 63, lo = lane & 15, hi = lane >> 4;
  const int toff = (wid * 7) & 31;               // tile desync (order-invariant sum)

  const f32x4 ZERO4 = {0.f, 0.f, 0.f, 0.f};
  const float QSCALE = 0.125f * 1.44269504088896f;
  const int qrow = qt*64 + w*16 + lo;
  bfv8 qf0, qf1;
  {
    const float* qp = Qf + ((size_t)(b*2048 + qrow))*1024 + h*64 + hi*8;
    qf0 = cvt8s(qp, QSCALE);
    qf1 = cvt8s(qp + 32, QSCALE);
  }

  const short* ktb = Kt + ((size_t)(bh*32) << 12);
  const short* vtb = Vt + ((size_t)(bh*32) << 12);
  const short* kmb = kms + b*2048;
  const int ro  = lo*64 + hi*8;                  // fragment offset within a tile row-block

  f32x4 acc[4];
  #pragma unroll
  for (int t2=0;t2<4;++t2) acc[t2] = ZERO4;
  f32x4 accL = ZERO4;

  for (int i = 0; i < 32; ++i){
    const int tcur = (toff + i) & 31;
    const short* kT = ktb + ((size_t)tcur << 12);
    const short* vT = vtb + ((size_t)tcur << 12);
    const short* kmrow = kmb + tcur*64;
    bfv8 kmf0 = *(const bfv8*)(kmrow + hi*8);
    bfv8 kmf1 = *(const bfv8*)(kmrow + 32 + hi*8);

    // S^T = K*Q^T (C-init 0), P = exp2(S)  (masked keys neutralized by V=0)
    u32 pk[8];
    __builtin_amdgcn_s_setprio(1);
    #pragma unroll
    for (int t=0;t<4;++t){
      const short* krow = kT + t*1024 + ro;      // row = t*16+lo, d-chunk hi
      bfv8 kf0 = *(const bfv8*)(krow);
      bfv8 kf1 = *(const bfv8*)(krow + 32);
      f32x4 c = MFMA16(kf0, qf0, ZERO4);
      c = MFMA16(kf1, qf1, c);
      float p0 = __builtin_amdgcn_exp2f(c[0]);
      float p1 = __builtin_amdgcn_exp2f(c[1]);
      float p2 = __builtin_amdgcn_exp2f(c[2]);
      float p3 = __builtin_amdgcn_exp2f(c[3]);
      pk[2*t]   = pk2(p0, p1);
      pk[2*t+1] = pk2(p2, p3);
    }
    __builtin_amdgcn_s_setprio(0);
    u32x4 pw0 = {pk[0],pk[1],pk[2],pk[3]};
    u32x4 pw1 = {pk[4],pk[5],pk[6],pk[7]};
    bfv8 pb0 = *(bfv8*)&pw0, pb1 = *(bfv8*)&pw1;

    // l += masked colsum(P) ; O^T += V^T * P^T  (V frags direct from global)
    __builtin_amdgcn_s_setprio(1);
    accL = MFMA16(kmf0, pb0, accL);
    accL = MFMA16(kmf1, pb1, accL);
    #pragma unroll
    for (int t2=0;t2<4;++t2){
      const short* vrow = vT + t2*1024 + ro;     // d-row = t2*16+lo, slot-chunk hi
      bfv8 vf0 = *(const bfv8*)(vrow);
      bfv8 vf1 = *(const bfv8*)(vrow + 32);
      acc[t2] = MFMA16(vf0, pb0, acc[t2]);
      acc[t2] = MFMA16(vf1, pb1, acc[t2]);
    }
    __builtin_amdgcn_s_setprio(0);
  }

  // epilogue: accL rows identical = masked l(q=lo); l==0 => fully-masked row
  float l = accL[0];
  float inv = (l > 0.f) ? 1.0f/l : 0.f;
  if (qmask[b*2048 + qrow] == 0) inv = 0.f;
  u32* xp = (u32*)(X + ((size_t)(b*2048 + qrow))*1024 + h*64);
  #pragma unroll
  for (int t2=0;t2<4;++t2){
    xp[t2*8 + 2*hi]     = pk2(acc[t2][0]*inv, acc[t2][1]*inv);
    xp[t2*8 + 2*hi + 1] = pk2(acc[t2][2]*inv, acc[t2][3]*inv);
  }
}

// Y[4096,1024](fp32) = X(bf16) @ Wo^T(bf16) + bo.  (round-20 green, unchanged)
__global__ __launch_bounds__(512, 1) void proj4(const short* __restrict__ X, const short* __restrict__ Wb,
                                                const float* __restrict__ bo, float* __restrict__ Y){
  __shared__ __align__(16) short xl[4][128][32];
  __shared__ __align__(16) short wl[4][128][32];
  const int bid = blockIdx.x;
  const int xcd = bid & 7, ii = bid >> 3;
  const int by = xcd*4 + (ii >> 3);
  const int bx = ii & 7;
  const int tid = threadIdx.x;
  const int w = tid >> 6, lane = tid & 63, lo = lane & 15, hi = lane >> 4;
  const int wr = w >> 2, wc = w & 3;
  const int brow = by*128, bcol = bx*128;
  const f32x4 ZERO4 = {0.f, 0.f, 0.f, 0.f};

  const int ci = w*64 + lane;
  const int rX = ci >> 2, csX = ci & 3;
  const short* xs = X  + (size_t)(brow + rX)*1024 + ((csX ^ (rX & 3)))*8;
  const short* ws = Wb + (size_t)(bcol + rX)*1024 + ((csX ^ (rX & 3)))*8;
  const int csA = (hi ^ (lo & 3)) * 8;

  f32x4 acc[4][2];
  #pragma unroll
  for (int i=0;i<4;++i){ acc[i][0] = ZERO4; acc[i][1] = ZERO4; }

  #pragma unroll
  for (int p = 0; p < 3; ++p){
    glds16(xs + p*32, &xl[p][0][0] + w*512);
    asm volatile("" ::: "memory");
    glds16(ws + p*32, &wl[p][0][0] + w*512);
    asm volatile("" ::: "memory");
  }

  for (int kt = 0; kt < 32; ++kt){
    asm volatile("s_waitcnt vmcnt(4)" ::: "memory");
    __builtin_amdgcn_s_barrier();
    __builtin_amdgcn_sched_barrier(0);
    {
      const int tn = (kt + 3) & 31, bn = (kt + 3) & 3;
      glds16(xs + tn*32, &xl[bn][0][0] + w*512);
      asm volatile("" ::: "memory");
      glds16(ws + tn*32, &wl[bn][0][0] + w*512);
      asm volatile("" ::: "memory");
    }
    const short* xc  = &xl[kt & 3][0][0];
    const short* wcp = &wl[kt & 3][0][0];
    bfv8 a[4], bb[2];
    #pragma unroll
    for (int i=0;i<4;++i) a[i]  = *(const bfv8*)(xc  + (wr*64 + i*16 + lo)*32 + csA);
    #pragma unroll
    for (int j=0;j<2;++j) bb[j] = *(const bfv8*)(wcp + (wc*32 + j*16 + lo)*32 + csA);
    __builtin_amdgcn_s_setprio(1);
    #pragma unroll
    for (int i=0;i<4;++i){
      acc[i][0] = MFMA16(a[i], bb[0], acc[i][0]);
      acc[i][1] = MFMA16(a[i], bb[1], acc[i][1]);
    }
    __builtin_amdgcn_s_setprio(0);
  }
  asm volatile("s_waitcnt vmcnt(0)" ::: "memory");

  float bv[2];
  bv[0] = bo[bcol + wc*32 + lo];
  bv[1] = bo[bcol + wc*32 + 16 + lo];
  #pragma unroll
  for (int i=0;i<4;++i){
    #pragma unroll
    for (int r=0;r<4;++r){
      size_t row = (size_t)(brow + wr*64 + i*16 + hi*4 + r);
      float* yp = Y + row*1024 + bcol + wc*32 + lo;
      yp[0]  = acc[i][0][r] + bv[0];
      yp[16] = acc[i][1][r] + bv[1];
    }
  }
}

extern "C" void kernel_launch(void* const* d_in, const int* in_sizes, int n_in,
                              void* d_out, int out_size, void* d_ws, size_t ws_size,
                              hipStream_t stream){
  const float* Q   = (const float*)d_in[0];
  const float* K   = (const float*)d_in[1];
  const float* V   = (const float*)d_in[2];
  const int* key_mask   = (const int*)d_in[3];
  const int* query_mask = (const int*)d_in[4];
  const float* Wo  = (const float*)d_in[5];
  const float* bo  = (const float*)d_in[6];

  short* Ktw = (short*)d_ws;            // 8 MB plain K tiles
  short* Vtw = Ktw + 4194304;           // 8 MB V^T sigma64 tiles (masked)
  short* Wb  = Vtw + 4194304;           // 2 MB bf16 Wo
  short* Xb  = Wb + 1048576;            // 8 MB attention output
  short* kms = Xb + 4194304;            // 8 KB sigma64 bf16 key-mask frags

  prep<<<3600,256,0,stream>>>(K, V, Wo, key_mask, Ktw, Vtw, Wb, kms);
  attn15<<<1024,256,0,stream>>>(Ktw, Vtw, Q, kms, query_mask, Xb);
  proj4<<<256,512,0,stream>>>(Xb, Wb, bo, (float*)d_out);
}

// Round 25
// 75.912 us; speedup vs baseline: 3.5464x; 3.5464x over previous
//
#include <hip/hip_runtime.h>

typedef __bf16 bfv8 __attribute__((ext_vector_type(8)));
typedef float f32x4 __attribute__((ext_vector_type(4)));
typedef short s16x8 __attribute__((ext_vector_type(8)));
typedef unsigned int u32;
typedef unsigned int u32x4 __attribute__((ext_vector_type(4)));

#define MFMA16(a,b,c) __builtin_amdgcn_mfma_f32_16x16x32_bf16((a),(b),(c),0,0,0)

__device__ __forceinline__ u32 pk2(float a, float b){
  u32 r; asm("v_cvt_pk_bf16_f32 %0, %1, %2" : "=v"(r) : "v"(a), "v"(b)); return r;
}
__device__ __forceinline__ bfv8 cvt8s(const float* p, float s){
  u32x4 r;
  #pragma unroll
  for (int j=0;j<4;++j) r[j] = pk2(p[2*j]*s, p[2*j+1]*s);
  return *(bfv8*)&r;
}
// async global->LDS, 16B/lane; LDS dest = wave-uniform base (+lane*16 by HW)
__device__ __forceinline__ void glds16(const short* g, short* l){
  __builtin_amdgcn_global_load_lds(
      (const __attribute__((address_space(1))) u32*)g,
      (__attribute__((address_space(3))) u32*)l, 16, 0, 0);
}

// Fused prep (sigma64, swizzled tiles — round-14/20 green)
__global__ __launch_bounds__(256) void prep(const float* __restrict__ K, const float* __restrict__ V,
                                            const float* __restrict__ Wo, const int* __restrict__ km,
                                            short* __restrict__ Kt, short* __restrict__ Vt,
                                            short* __restrict__ Wb, short* __restrict__ kms){
  __shared__ short tl[64][65];
  const int bid = blockIdx.x, tid = threadIdx.x;
  if (bid < 2048){
    int idx = bid*256 + tid;
    int cs = idx & 7, r = (idx >> 3) & 63, kt = (idx >> 9) & 31, bh = idx >> 14;
    int b = bh >> 4, h = bh & 15;
    int c = cs ^ (r & 7);
    const float* src = K + ((size_t)(b*2048 + kt*64 + r))*1024 + h*64 + c*8;
    float4 a = ((const float4*)src)[0], bb = ((const float4*)src)[1];
    u32x4 o;
    o[0]=pk2(a.x,a.y); o[1]=pk2(a.z,a.w); o[2]=pk2(bb.x,bb.y); o[3]=pk2(bb.z,bb.w);
    ((u32x4*)Kt)[idx] = o;
  } else if (bid < 3072){
    int vb = bid - 2048;
    int kt = vb & 31, bh = vb >> 5;
    int b = bh >> 4, h = bh & 15;
    {
      int s = tid >> 2, d0 = (tid & 3) * 16;
      float kmv = (km[b*2048 + kt*64 + s] != 0) ? 1.0f : 0.0f;   // fold mask into V
      const float* src = V + ((size_t)(b*2048 + kt*64 + s))*1024 + h*64 + d0;
      #pragma unroll
      for (int j = 0; j < 4; ++j){
        float4 v = ((const float4*)src)[j];
        tl[d0+4*j+0][s] = (short)(pk2(v.x*kmv, 0.f) & 0xffff);
        tl[d0+4*j+1][s] = (short)(pk2(v.y*kmv, 0.f) & 0xffff);
        tl[d0+4*j+2][s] = (short)(pk2(v.z*kmv, 0.f) & 0xffff);
        tl[d0+4*j+3][s] = (short)(pk2(v.w*kmv, 0.f) & 0xffff);
      }
    }
    __syncthreads();
    {
      int r = tid >> 2, cp = (tid & 3) * 2;
      short* dst = Vt + (((size_t)(bh*32 + kt)*64 + r) << 6);
      #pragma unroll
      for (int q = 0; q < 2; ++q){
        int cs = cp + q;
        int c = cs ^ (r & 7);
        s16x8 o;
        #pragma unroll
        for (int j = 0; j < 8; ++j){
          int s = c*8 + j;
          int sg = s >> 2, rr = s & 3;
          int t = (sg >> 3)*2 + (sg & 1);
          int a = (sg >> 1) & 3;
          int kap = t*16 + a*4 + rr;
          o[j] = tl[r][kap];
        }
        *(s16x8*)(dst + cs*8) = o;
      }
    }
  } else if (bid < 3584){
    int i = (bid - 3072)*256 + tid;
    const float* p = Wo + (size_t)i*8;
    u32x4 o;
    o[0]=pk2(p[0],p[1]); o[1]=pk2(p[2],p[3]); o[2]=pk2(p[4],p[5]); o[3]=pk2(p[6],p[7]);
    ((u32x4*)Wb)[i] = o;
  } else {
    int i = (bid - 3584)*256 + tid;   // 0..4095: [b][kt][slot]
    if (i < 4096){
      int bb = i >> 11, kt = (i >> 6) & 31, s = i & 63;
      int rr = s & 3, a = (s >> 3) & 3, t = ((s >> 5) & 1)*2 + ((s >> 2) & 1);
      int key = t*16 + a*4 + rr;     // sigma^-1(slot)
      kms[i] = (km[bb*2048 + kt*64 + key] != 0) ? (short)0x3F80 : (short)0;
    }
  }
}

// Flash attention (round-17/20 green): DUAL-Q, 4 waves x 32 q-rows, grid 512
// (2 blocks/CU). Ring-4, counted vmcnt(8), stage-after-barrier, sched_barrier.
__global__ __launch_bounds__(256, 2) void attn11(const short* __restrict__ Kt, const short* __restrict__ Vt,
                                                 const float* __restrict__ Qf, const short* __restrict__ kms,
                                                 const int* __restrict__ qmask, short* __restrict__ X){
  __shared__ __align__(16) short kl[4][64][64];
  __shared__ __align__(16) short vl[4][64][64];
  __shared__ __align__(16) short kml[32][64];
  const int wid = blockIdx.x;
  const int bh = (wid & 7)*4 + (wid >> 7);
  const int qt = (wid >> 3) & 15;
  const int b = bh >> 4, h = bh & 15;
  const int tid = threadIdx.x;
  const int w = tid >> 6, lane = tid & 63, lo = lane & 15, hi = lane >> 4;
  const int toff = (wid * 7) & 31;

  const f32x4 ZERO4 = {0.f, 0.f, 0.f, 0.f};
  const float QSCALE = 0.125f * 1.44269504088896f;
  const int qrowA = qt*128 + w*32 + lo;
  const int qrowB = qrowA + 16;
  bfv8 qa0, qa1, qb0, qb1;
  {
    const float* qp = Qf + ((size_t)(b*2048 + qrowA))*1024 + h*64 + hi*8;
    qa0 = cvt8s(qp, QSCALE);         qa1 = cvt8s(qp + 32, QSCALE);
    qb0 = cvt8s(qp + 16384, QSCALE); qb1 = cvt8s(qp + 16416, QSCALE);
  }

  glds16(kms + b*2048 + w*512 + lane*8, &kml[0][0] + w*512);
  asm volatile("s_waitcnt vmcnt(0)" ::: "memory");
  __builtin_amdgcn_s_barrier();
  __builtin_amdgcn_sched_barrier(0);

  const short* ktb = Kt + ((size_t)(bh*32) << 12);
  const short* vtb = Vt + ((size_t)(bh*32) << 12);
  const int sg0 = w*1024 + lane*8;
  const int sg1 = sg0 + 512;
  const int csK = (hi ^ (lo & 7)) * 8;

  f32x4 accA[4], accB[4];
  #pragma unroll
  for (int t2=0;t2<4;++t2){ accA[t2] = ZERO4; accB[t2] = ZERO4; }
  f32x4 accLa = ZERO4, accLb = ZERO4;

  #pragma unroll
  for (int p = 0; p < 3; ++p){
    const size_t tb_ = (size_t)((toff + p) & 31) << 12;
    glds16(ktb + tb_ + sg0, &kl[p][0][0] + w*1024);
    asm volatile("" ::: "memory");
    glds16(ktb + tb_ + sg1, &kl[p][0][0] + w*1024 + 512);
    asm volatile("" ::: "memory");
    glds16(vtb + tb_ + sg0, &vl[p][0][0] + w*1024);
    asm volatile("" ::: "memory");
    glds16(vtb + tb_ + sg1, &vl[p][0][0] + w*1024 + 512);
    asm volatile("" ::: "memory");
  }

  for (int i = 0; i < 32; ++i){
    asm volatile("s_waitcnt vmcnt(8)" ::: "memory");
    __builtin_amdgcn_s_barrier();
    __builtin_amdgcn_sched_barrier(0);
    {
      const int tn = (toff + i + 3) & 31, bn = (i + 3) & 3;
      const size_t tb_ = (size_t)tn << 12;
      glds16(ktb + tb_ + sg0, &kl[bn][0][0] + w*1024);
      asm volatile("" ::: "memory");
      glds16(ktb + tb_ + sg1, &kl[bn][0][0] + w*1024 + 512);
      asm volatile("" ::: "memory");
      glds16(vtb + tb_ + sg0, &vl[bn][0][0] + w*1024);
      asm volatile("" ::: "memory");
      glds16(vtb + tb_ + sg1, &vl[bn][0][0] + w*1024 + 512);
      asm volatile("" ::: "memory");
    }
    const short (*kc)[64] = kl[i & 3];
    const short (*vc)[64] = vl[i & 3];
    const short* kmrow = &kml[(toff + i) & 31][0];
    bfv8 kmf0 = *(const bfv8*)(kmrow + hi*8);
    bfv8 kmf1 = *(const bfv8*)(kmrow + 32 + hi*8);

    u32 pka[8], pkb[8];
    __builtin_amdgcn_s_setprio(1);
    #pragma unroll
    for (int t=0;t<4;++t){
      const short* rowp = &kc[t*16+lo][0];
      bfv8 kf0 = *(const bfv8*)(rowp + csK);
      bfv8 kf1 = *(const bfv8*)(rowp + (csK ^ 32));
      f32x4 ca = MFMA16(kf0, qa0, ZERO4);
      ca = MFMA16(kf1, qa1, ca);
      f32x4 cb = MFMA16(kf0, qb0, ZERO4);
      cb = MFMA16(kf1, qb1, cb);
      float a0 = __builtin_amdgcn_exp2f(ca[0]);
      float a1 = __builtin_amdgcn_exp2f(ca[1]);
      float a2 = __builtin_amdgcn_exp2f(ca[2]);
      float a3 = __builtin_amdgcn_exp2f(ca[3]);
      float b0 = __builtin_amdgcn_exp2f(cb[0]);
      float b1 = __builtin_amdgcn_exp2f(cb[1]);
      float b2 = __builtin_amdgcn_exp2f(cb[2]);
      float b3 = __builtin_amdgcn_exp2f(cb[3]);
      pka[2*t]   = pk2(a0, a1); pka[2*t+1] = pk2(a2, a3);
      pkb[2*t]   = pk2(b0, b1); pkb[2*t+1] = pk2(b2, b3);
    }
    __builtin_amdgcn_s_setprio(0);
    u32x4 pwa0 = {pka[0],pka[1],pka[2],pka[3]};
    u32x4 pwa1 = {pka[4],pka[5],pka[6],pka[7]};
    u32x4 pwb0 = {pkb[0],pkb[1],pkb[2],pkb[3]};
    u32x4 pwb1 = {pkb[4],pkb[5],pkb[6],pkb[7]};
    bfv8 pa0 = *(bfv8*)&pwa0, pa1 = *(bfv8*)&pwa1;
    bfv8 pb0 = *(bfv8*)&pwb0, pb1 = *(bfv8*)&pwb1;

    __builtin_amdgcn_s_setprio(1);
    accLa = MFMA16(kmf0, pa0, accLa);
    accLa = MFMA16(kmf1, pa1, accLa);
    accLb = MFMA16(kmf0, pb0, accLb);
    accLb = MFMA16(kmf1, pb1, accLb);
    #pragma unroll
    for (int t2=0;t2<4;++t2){
      const short* rowp = &vc[t2*16+lo][0];
      bfv8 vf0 = *(const bfv8*)(rowp + csK);
      bfv8 vf1 = *(const bfv8*)(rowp + (csK ^ 32));
      accA[t2] = MFMA16(vf0, pa0, accA[t2]);
      accA[t2] = MFMA16(vf1, pa1, accA[t2]);
      accB[t2] = MFMA16(vf0, pb0, accB[t2]);
      accB[t2] = MFMA16(vf1, pb1, accB[t2]);
    }
    __builtin_amdgcn_s_setprio(0);
  }
  asm volatile("s_waitcnt vmcnt(0)" ::: "memory");

  float la = accLa[0], lb = accLb[0];
  float invA = (la > 0.f) ? 1.0f/la : 0.f;
  float invB = (lb > 0.f) ? 1.0f/lb : 0.f;
  if (qmask[b*2048 + qrowA] == 0) invA = 0.f;
  if (qmask[b*2048 + qrowB] == 0) invB = 0.f;
  u32* xpA = (u32*)(X + ((size_t)(b*2048 + qrowA))*1024 + h*64);
  u32* xpB = (u32*)(X + ((size_t)(b*2048 + qrowB))*1024 + h*64);
  #pragma unroll
  for (int t2=0;t2<4;++t2){
    xpA[t2*8 + 2*hi]     = pk2(accA[t2][0]*invA, accA[t2][1]*invA);
    xpA[t2*8 + 2*hi + 1] = pk2(accA[t2][2]*invA, accA[t2][3]*invA);
    xpB[t2*8 + 2*hi]     = pk2(accB[t2][0]*invB, accB[t2][1]*invB);
    xpB[t2*8 + 2*hi + 1] = pk2(accB[t2][2]*invB, accB[t2][3]*invB);
  }
}

// Y[4096,1024](fp32) = X(bf16) @ Wo^T(bf16) + bo.  (round-20 green)
__global__ __launch_bounds__(512, 1) void proj4(const short* __restrict__ X, const short* __restrict__ Wb,
                                                const float* __restrict__ bo, float* __restrict__ Y){
  __shared__ __align__(16) short xl[4][128][32];
  __shared__ __align__(16) short wl[4][128][32];
  const int bid = blockIdx.x;
  const int xcd = bid & 7, ii = bid >> 3;
  const int by = xcd*4 + (ii >> 3);
  const int bx = ii & 7;
  const int tid = threadIdx.x;
  const int w = tid >> 6, lane = tid & 63, lo = lane & 15, hi = lane >> 4;
  const int wr = w >> 2, wc = w & 3;
  const int brow = by*128, bcol = bx*128;
  const f32x4 ZERO4 = {0.f, 0.f, 0.f, 0.f};

  const int ci = w*64 + lane;
  const int rX = ci >> 2, csX = ci & 3;
  const short* xs = X  + (size_t)(brow + rX)*1024 + ((csX ^ (rX & 3)))*8;
  const short* ws = Wb + (size_t)(bcol + rX)*1024 + ((csX ^ (rX & 3)))*8;
  const int csA = (hi ^ (lo & 3)) * 8;

  f32x4 acc[4][2];
  #pragma unroll
  for (int i=0;i<4;++i){ acc[i][0] = ZERO4; acc[i][1] = ZERO4; }

  #pragma unroll
  for (int p = 0; p < 3; ++p){
    glds16(xs + p*32, &xl[p][0][0] + w*512);
    asm volatile("" ::: "memory");
    glds16(ws + p*32, &wl[p][0][0] + w*512);
    asm volatile("" ::: "memory");
  }

  for (int kt = 0; kt < 32; ++kt){
    asm volatile("s_waitcnt vmcnt(4)" ::: "memory");
    __builtin_amdgcn_s_barrier();
    __builtin_amdgcn_sched_barrier(0);
    {
      const int tn = (kt + 3) & 31, bn = (kt + 3) & 3;
      glds16(xs + tn*32, &xl[bn][0][0] + w*512);
      asm volatile("" ::: "memory");
      glds16(ws + tn*32, &wl[bn][0][0] + w*512);
      asm volatile("" ::: "memory");
    }
    const short* xc  = &xl[kt & 3][0][0];
    const short* wcp = &wl[kt & 3][0][0];
    bfv8 a[4], bb[2];
    #pragma unroll
    for (int i=0;i<4;++i) a[i]  = *(const bfv8*)(xc  + (wr*64 + i*16 + lo)*32 + csA);
    #pragma unroll
    for (int j=0;j<2;++j) bb[j] = *(const bfv8*)(wcp + (wc*32 + j*16 + lo)*32 + csA);
    __builtin_amdgcn_s_setprio(1);
    #pragma unroll
    for (int i=0;i<4;++i){
      acc[i][0] = MFMA16(a[i], bb[0], acc[i][0]);
      acc[i][1] = MFMA16(a[i], bb[1], acc[i][1]);
    }
    __builtin_amdgcn_s_setprio(0);
  }
  asm volatile("s_waitcnt vmcnt(0)" ::: "memory");

  float bv[2];
  bv[0] = bo[bcol + wc*32 + lo];
  bv[1] = bo[bcol + wc*32 + 16 + lo];
  #pragma unroll
  for (int i=0;i<4;++i){
    #pragma unroll
    for (int r=0;r<4;++r){
      size_t row = (size_t)(brow + wr*64 + i*16 + hi*4 + r);
      float* yp = Y + row*1024 + bcol + wc*32 + lo;
      yp[0]  = acc[i][0][r] + bv[0];
      yp[16] = acc[i][1][r] + bv[1];
    }
  }
}

extern "C" void kernel_launch(void* const* d_in, const int* in_sizes, int n_in,
                              void* d_out, int out_size, void* d_ws, size_t ws_size,
                              hipStream_t stream){
  const float* Q   = (const float*)d_in[0];
  const float* K   = (const float*)d_in[1];
  const float* V   = (const float*)d_in[2];
  const int* key_mask   = (const int*)d_in[3];
  const int* query_mask = (const int*)d_in[4];
  const float* Wo  = (const float*)d_in[5];
  const float* bo  = (const float*)d_in[6];

  short* Ktw = (short*)d_ws;            // 8 MB swizzled K tiles
  short* Vtw = Ktw + 4194304;           // 8 MB swizzled+masked V^T tiles (sigma64)
  short* Wb  = Vtw + 4194304;           // 2 MB bf16 Wo
  short* Xb  = Wb + 1048576;            // 8 MB attention output
  short* kms = Xb + 4194304;            // 8 KB sigma64 bf16 key-mask frags

  prep<<<3600,256,0,stream>>>(K, V, Wo, key_mask, Ktw, Vtw, Wb, kms);
  attn11<<<512,256,0,stream>>>(Ktw, Vtw, Q, kms, query_mask, Xb);
  proj4<<<256,512,0,stream>>>(Xb, Wb, bo, (float*)d_out);
}

// Round 26
// 71.444 us; speedup vs baseline: 3.7682x; 1.0625x over previous
//
#include <hip/hip_runtime.h>

typedef __bf16 bfv8 __attribute__((ext_vector_type(8)));
typedef float f32x4 __attribute__((ext_vector_type(4)));
typedef short s16x8 __attribute__((ext_vector_type(8)));
typedef unsigned int u32;
typedef unsigned int u32x4 __attribute__((ext_vector_type(4)));

#define MFMA16(a,b,c) __builtin_amdgcn_mfma_f32_16x16x32_bf16((a),(b),(c),0,0,0)

__device__ __forceinline__ u32 pk2(float a, float b){
  u32 r; asm("v_cvt_pk_bf16_f32 %0, %1, %2" : "=v"(r) : "v"(a), "v"(b)); return r;
}
__device__ __forceinline__ bfv8 cvt8s(const float* p, float s){
  u32x4 r;
  #pragma unroll
  for (int j=0;j<4;++j) r[j] = pk2(p[2*j]*s, p[2*j+1]*s);
  return *(bfv8*)&r;
}
// async global->LDS, 16B/lane; LDS dest = wave-uniform base (+lane*16 by HW)
__device__ __forceinline__ void glds16(const short* g, short* l){
  __builtin_amdgcn_global_load_lds(
      (const __attribute__((address_space(1))) u32*)g,
      (__attribute__((address_space(3))) u32*)l, 16, 0, 0);
}

// Fused prep (sigma64, swizzled tiles — green, unchanged)
__global__ __launch_bounds__(256) void prep(const float* __restrict__ K, const float* __restrict__ V,
                                            const float* __restrict__ Wo, const int* __restrict__ km,
                                            short* __restrict__ Kt, short* __restrict__ Vt,
                                            short* __restrict__ Wb, short* __restrict__ kms){
  __shared__ short tl[64][65];
  const int bid = blockIdx.x, tid = threadIdx.x;
  if (bid < 2048){
    int idx = bid*256 + tid;
    int cs = idx & 7, r = (idx >> 3) & 63, kt = (idx >> 9) & 31, bh = idx >> 14;
    int b = bh >> 4, h = bh & 15;
    int c = cs ^ (r & 7);
    const float* src = K + ((size_t)(b*2048 + kt*64 + r))*1024 + h*64 + c*8;
    float4 a = ((const float4*)src)[0], bb = ((const float4*)src)[1];
    u32x4 o;
    o[0]=pk2(a.x,a.y); o[1]=pk2(a.z,a.w); o[2]=pk2(bb.x,bb.y); o[3]=pk2(bb.z,bb.w);
    ((u32x4*)Kt)[idx] = o;
  } else if (bid < 3072){
    int vb = bid - 2048;
    int kt = vb & 31, bh = vb >> 5;
    int b = bh >> 4, h = bh & 15;
    {
      int s = tid >> 2, d0 = (tid & 3) * 16;
      float kmv = (km[b*2048 + kt*64 + s] != 0) ? 1.0f : 0.0f;   // fold mask into V
      const float* src = V + ((size_t)(b*2048 + kt*64 + s))*1024 + h*64 + d0;
      #pragma unroll
      for (int j = 0; j < 4; ++j){
        float4 v = ((const float4*)src)[j];
        tl[d0+4*j+0][s] = (short)(pk2(v.x*kmv, 0.f) & 0xffff);
        tl[d0+4*j+1][s] = (short)(pk2(v.y*kmv, 0.f) & 0xffff);
        tl[d0+4*j+2][s] = (short)(pk2(v.z*kmv, 0.f) & 0xffff);
        tl[d0+4*j+3][s] = (short)(pk2(v.w*kmv, 0.f) & 0xffff);
      }
    }
    __syncthreads();
    {
      int r = tid >> 2, cp = (tid & 3) * 2;
      short* dst = Vt + (((size_t)(bh*32 + kt)*64 + r) << 6);
      #pragma unroll
      for (int q = 0; q < 2; ++q){
        int cs = cp + q;
        int c = cs ^ (r & 7);
        s16x8 o;
        #pragma unroll
        for (int j = 0; j < 8; ++j){
          int s = c*8 + j;
          int sg = s >> 2, rr = s & 3;
          int t = (sg >> 3)*2 + (sg & 1);
          int a = (sg >> 1) & 3;
          int kap = t*16 + a*4 + rr;
          o[j] = tl[r][kap];
        }
        *(s16x8*)(dst + cs*8) = o;
      }
    }
  } else if (bid < 3584){
    int i = (bid - 3072)*256 + tid;
    const float* p = Wo + (size_t)i*8;
    u32x4 o;
    o[0]=pk2(p[0],p[1]); o[1]=pk2(p[2],p[3]); o[2]=pk2(p[4],p[5]); o[3]=pk2(p[6],p[7]);
    ((u32x4*)Wb)[i] = o;
  } else {
    int i = (bid - 3584)*256 + tid;   // 0..4095: [b][kt][slot]
    if (i < 4096){
      int bb = i >> 11, kt = (i >> 6) & 31, s = i & 63;
      int rr = s & 3, a = (s >> 3) & 3, t = ((s >> 5) & 1)*2 + ((s >> 2) & 1);
      int key = t*16 + a*4 + rr;     // sigma^-1(slot)
      kms[i] = (km[bb*2048 + kt*64 + key] != 0) ? (short)0x3F80 : (short)0;
    }
  }
}

// Flash attention (green, unchanged): DUAL-Q, 4 waves x 32 q-rows, grid 512
// (2 blocks/CU). Ring-4, counted vmcnt(8), stage-after-barrier, sched_barrier.
__global__ __launch_bounds__(256, 2) void attn11(const short* __restrict__ Kt, const short* __restrict__ Vt,
                                                 const float* __restrict__ Qf, const short* __restrict__ kms,
                                                 const int* __restrict__ qmask, short* __restrict__ X){
  __shared__ __align__(16) short kl[4][64][64];
  __shared__ __align__(16) short vl[4][64][64];
  __shared__ __align__(16) short kml[32][64];
  const int wid = blockIdx.x;
  const int bh = (wid & 7)*4 + (wid >> 7);
  const int qt = (wid >> 3) & 15;
  const int b = bh >> 4, h = bh & 15;
  const int tid = threadIdx.x;
  const int w = tid >> 6, lane = tid & 63, lo = lane & 15, hi = lane >> 4;
  const int toff = (wid * 7) & 31;

  const f32x4 ZERO4 = {0.f, 0.f, 0.f, 0.f};
  const float QSCALE = 0.125f * 1.44269504088896f;
  const int qrowA = qt*128 + w*32 + lo;
  const int qrowB = qrowA + 16;
  bfv8 qa0, qa1, qb0, qb1;
  {
    const float* qp = Qf + ((size_t)(b*2048 + qrowA))*1024 + h*64 + hi*8;
    qa0 = cvt8s(qp, QSCALE);         qa1 = cvt8s(qp + 32, QSCALE);
    qb0 = cvt8s(qp + 16384, QSCALE); qb1 = cvt8s(qp + 16416, QSCALE);
  }

  glds16(kms + b*2048 + w*512 + lane*8, &kml[0][0] + w*512);
  asm volatile("s_waitcnt vmcnt(0)" ::: "memory");
  __builtin_amdgcn_s_barrier();
  __builtin_amdgcn_sched_barrier(0);

  const short* ktb = Kt + ((size_t)(bh*32) << 12);
  const short* vtb = Vt + ((size_t)(bh*32) << 12);
  const int sg0 = w*1024 + lane*8;
  const int sg1 = sg0 + 512;
  const int csK = (hi ^ (lo & 7)) * 8;

  f32x4 accA[4], accB[4];
  #pragma unroll
  for (int t2=0;t2<4;++t2){ accA[t2] = ZERO4; accB[t2] = ZERO4; }
  f32x4 accLa = ZERO4, accLb = ZERO4;

  #pragma unroll
  for (int p = 0; p < 3; ++p){
    const size_t tb_ = (size_t)((toff + p) & 31) << 12;
    glds16(ktb + tb_ + sg0, &kl[p][0][0] + w*1024);
    asm volatile("" ::: "memory");
    glds16(ktb + tb_ + sg1, &kl[p][0][0] + w*1024 + 512);
    asm volatile("" ::: "memory");
    glds16(vtb + tb_ + sg0, &vl[p][0][0] + w*1024);
    asm volatile("" ::: "memory");
    glds16(vtb + tb_ + sg1, &vl[p][0][0] + w*1024 + 512);
    asm volatile("" ::: "memory");
  }

  for (int i = 0; i < 32; ++i){
    asm volatile("s_waitcnt vmcnt(8)" ::: "memory");
    __builtin_amdgcn_s_barrier();
    __builtin_amdgcn_sched_barrier(0);
    {
      const int tn = (toff + i + 3) & 31, bn = (i + 3) & 3;
      const size_t tb_ = (size_t)tn << 12;
      glds16(ktb + tb_ + sg0, &kl[bn][0][0] + w*1024);
      asm volatile("" ::: "memory");
      glds16(ktb + tb_ + sg1, &kl[bn][0][0] + w*1024 + 512);
      asm volatile("" ::: "memory");
      glds16(vtb + tb_ + sg0, &vl[bn][0][0] + w*1024);
      asm volatile("" ::: "memory");
      glds16(vtb + tb_ + sg1, &vl[bn][0][0] + w*1024 + 512);
      asm volatile("" ::: "memory");
    }
    const short (*kc)[64] = kl[i & 3];
    const short (*vc)[64] = vl[i & 3];
    const short* kmrow = &kml[(toff + i) & 31][0];
    bfv8 kmf0 = *(const bfv8*)(kmrow + hi*8);
    bfv8 kmf1 = *(const bfv8*)(kmrow + 32 + hi*8);

    u32 pka[8], pkb[8];
    __builtin_amdgcn_s_setprio(1);
    #pragma unroll
    for (int t=0;t<4;++t){
      const short* rowp = &kc[t*16+lo][0];
      bfv8 kf0 = *(const bfv8*)(rowp + csK);
      bfv8 kf1 = *(const bfv8*)(rowp + (csK ^ 32));
      f32x4 ca = MFMA16(kf0, qa0, ZERO4);
      ca = MFMA16(kf1, qa1, ca);
      f32x4 cb = MFMA16(kf0, qb0, ZERO4);
      cb = MFMA16(kf1, qb1, cb);
      float a0 = __builtin_amdgcn_exp2f(ca[0]);
      float a1 = __builtin_amdgcn_exp2f(ca[1]);
      float a2 = __builtin_amdgcn_exp2f(ca[2]);
      float a3 = __builtin_amdgcn_exp2f(ca[3]);
      float b0 = __builtin_amdgcn_exp2f(cb[0]);
      float b1 = __builtin_amdgcn_exp2f(cb[1]);
      float b2 = __builtin_amdgcn_exp2f(cb[2]);
      float b3 = __builtin_amdgcn_exp2f(cb[3]);
      pka[2*t]   = pk2(a0, a1); pka[2*t+1] = pk2(a2, a3);
      pkb[2*t]   = pk2(b0, b1); pkb[2*t+1] = pk2(b2, b3);
    }
    __builtin_amdgcn_s_setprio(0);
    u32x4 pwa0 = {pka[0],pka[1],pka[2],pka[3]};
    u32x4 pwa1 = {pka[4],pka[5],pka[6],pka[7]};
    u32x4 pwb0 = {pkb[0],pkb[1],pkb[2],pkb[3]};
    u32x4 pwb1 = {pkb[4],pkb[5],pkb[6],pkb[7]};
    bfv8 pa0 = *(bfv8*)&pwa0, pa1 = *(bfv8*)&pwa1;
    bfv8 pb0 = *(bfv8*)&pwb0, pb1 = *(bfv8*)&pwb1;

    __builtin_amdgcn_s_setprio(1);
    accLa = MFMA16(kmf0, pa0, accLa);
    accLa = MFMA16(kmf1, pa1, accLa);
    accLb = MFMA16(kmf0, pb0, accLb);
    accLb = MFMA16(kmf1, pb1, accLb);
    #pragma unroll
    for (int t2=0;t2<4;++t2){
      const short* rowp = &vc[t2*16+lo][0];
      bfv8 vf0 = *(const bfv8*)(rowp + csK);
      bfv8 vf1 = *(const bfv8*)(rowp + (csK ^ 32));
      accA[t2] = MFMA16(vf0, pa0, accA[t2]);
      accA[t2] = MFMA16(vf1, pa1, accA[t2]);
      accB[t2] = MFMA16(vf0, pb0, accB[t2]);
      accB[t2] = MFMA16(vf1, pb1, accB[t2]);
    }
    __builtin_amdgcn_s_setprio(0);
  }
  asm volatile("s_waitcnt vmcnt(0)" ::: "memory");

  float la = accLa[0], lb = accLb[0];
  float invA = (la > 0.f) ? 1.0f/la : 0.f;
  float invB = (lb > 0.f) ? 1.0f/lb : 0.f;
  if (qmask[b*2048 + qrowA] == 0) invA = 0.f;
  if (qmask[b*2048 + qrowB] == 0) invB = 0.f;
  u32* xpA = (u32*)(X + ((size_t)(b*2048 + qrowA))*1024 + h*64);
  u32* xpB = (u32*)(X + ((size_t)(b*2048 + qrowB))*1024 + h*64);
  #pragma unroll
  for (int t2=0;t2<4;++t2){
    xpA[t2*8 + 2*hi]     = pk2(accA[t2][0]*invA, accA[t2][1]*invA);
    xpA[t2*8 + 2*hi + 1] = pk2(accA[t2][2]*invA, accA[t2][3]*invA);
    xpB[t2*8 + 2*hi]     = pk2(accB[t2][0]*invB, accB[t2][1]*invB);
    xpB[t2*8 + 2*hi + 1] = pk2(accB[t2][2]*invB, accB[t2][3]*invB);
  }
}

// Y[4096,1024](fp32) = X(bf16) @ Wo^T(bf16) + bo.
// NEW proj5: 128x128 tile, BK=64 (16 iterations), ring-4, 8 waves, grid 256
// (1 block/CU, 128 KB LDS). Same proven skeleton: stage-3-ahead, vmcnt(8),
// s_barrier + sched_barrier(0), wrapped-tail restage.
__global__ __launch_bounds__(512, 1) void proj5(const short* __restrict__ X, const short* __restrict__ Wb,
                                                const float* __restrict__ bo, float* __restrict__ Y){
  __shared__ __align__(16) short xl[4][128][64];   // 64 KB
  __shared__ __align__(16) short wl[4][128][64];   // 64 KB
  const int bid = blockIdx.x;
  const int xcd = bid & 7, ii = bid >> 3;
  const int by = xcd*4 + (ii >> 3);
  const int bx = ii & 7;
  const int tid = threadIdx.x;
  const int w = tid >> 6, lane = tid & 63, lo = lane & 15, hi = lane >> 4;
  const int wr = w >> 2, wc = w & 3;               // wave: rows wr*64, cols wc*32
  const int brow = by*128, bcol = bx*128;
  const f32x4 ZERO4 = {0.f, 0.f, 0.f, 0.f};

  // staging: per tile 1024 chunks (128 rows x 8); wave w, glds g: chunk = w*128+g*64+lane
  // src chunk c = cs ^ (r&7); glds g=1 is +8 rows (same swizzle phase)
  const int c0 = w*128 + lane;
  const int r0 = c0 >> 3;
  const int s0 = ((c0 & 7) ^ (r0 & 7)) * 8;
  const short* xs0 = X  + (size_t)(brow + r0)*1024 + s0;
  const short* xs1 = X  + (size_t)(brow + r0 + 8)*1024 + s0;
  const short* ws0 = Wb + (size_t)(bcol + r0)*1024 + s0;
  const short* ws1 = Wb + (size_t)(bcol + r0 + 8)*1024 + s0;
  const int csA = (hi ^ (lo & 7)) * 8;             // first k-half; second at ^32

  f32x4 acc[4][2];
  #pragma unroll
  for (int i=0;i<4;++i){ acc[i][0] = ZERO4; acc[i][1] = ZERO4; }

  // prologue: tiles 0,1,2 -> bufs 0,1,2 (4 glds/wave each)
  #pragma unroll
  for (int p = 0; p < 3; ++p){
    glds16(xs0 + p*64, &xl[p][0][0] + w*1024);
    asm volatile("" ::: "memory");
    glds16(xs1 + p*64, &xl[p][0][0] + w*1024 + 512);
    asm volatile("" ::: "memory");
    glds16(ws0 + p*64, &wl[p][0][0] + w*1024);
    asm volatile("" ::: "memory");
    glds16(ws1 + p*64, &wl[p][0][0] + w*1024 + 512);
    asm volatile("" ::: "memory");
  }

  for (int kt = 0; kt < 16; ++kt){
    asm volatile("s_waitcnt vmcnt(8)" ::: "memory");  // tile kt landed (2 newer x 4 loads)
    __builtin_amdgcn_s_barrier();
    __builtin_amdgcn_sched_barrier(0);
    {
      const int tn = (kt + 3) & 15, bn = (kt + 3) & 3;  // wrapped tail restage
      glds16(xs0 + tn*64, &xl[bn][0][0] + w*1024);
      asm volatile("" ::: "memory");
      glds16(xs1 + tn*64, &xl[bn][0][0] + w*1024 + 512);
      asm volatile("" ::: "memory");
      glds16(ws0 + tn*64, &wl[bn][0][0] + w*1024);
      asm volatile("" ::: "memory");
      glds16(ws1 + tn*64, &wl[bn][0][0] + w*1024 + 512);
      asm volatile("" ::: "memory");
    }
    const short* xc  = &xl[kt & 3][0][0];
    const short* wcp = &wl[kt & 3][0][0];
    __builtin_amdgcn_s_setprio(1);
    #pragma unroll
    for (int kh = 0; kh < 2; ++kh){
      const int co = csA ^ (kh * 32);
      bfv8 a[4], bb[2];
      #pragma unroll
      for (int i=0;i<4;++i) a[i]  = *(const bfv8*)(xc  + (wr*64 + i*16 + lo)*64 + co);
      #pragma unroll
      for (int j=0;j<2;++j) bb[j] = *(const bfv8*)(wcp + (wc*32 + j*16 + lo)*64 + co);
      #pragma unroll
      for (int i=0;i<4;++i){
        acc[i][0] = MFMA16(a[i], bb[0], acc[i][0]);
        acc[i][1] = MFMA16(a[i], bb[1], acc[i][1]);
      }
    }
    __builtin_amdgcn_s_setprio(0);
  }
  asm volatile("s_waitcnt vmcnt(0)" ::: "memory");

  float bv[2];
  bv[0] = bo[bcol + wc*32 + lo];
  bv[1] = bo[bcol + wc*32 + 16 + lo];
  #pragma unroll
  for (int i=0;i<4;++i){
    #pragma unroll
    for (int r=0;r<4;++r){
      size_t row = (size_t)(brow + wr*64 + i*16 + hi*4 + r);
      float* yp = Y + row*1024 + bcol + wc*32 + lo;
      yp[0]  = acc[i][0][r] + bv[0];
      yp[16] = acc[i][1][r] + bv[1];
    }
  }
}

extern "C" void kernel_launch(void* const* d_in, const int* in_sizes, int n_in,
                              void* d_out, int out_size, void* d_ws, size_t ws_size,
                              hipStream_t stream){
  const float* Q   = (const float*)d_in[0];
  const float* K   = (const float*)d_in[1];
  const float* V   = (const float*)d_in[2];
  const int* key_mask   = (const int*)d_in[3];
  const int* query_mask = (const int*)d_in[4];
  const float* Wo  = (const float*)d_in[5];
  const float* bo  = (const float*)d_in[6];

  short* Ktw = (short*)d_ws;            // 8 MB swizzled K tiles
  short* Vtw = Ktw + 4194304;           // 8 MB swizzled+masked V^T tiles (sigma64)
  short* Wb  = Vtw + 4194304;           // 2 MB bf16 Wo
  short* Xb  = Wb + 1048576;            // 8 MB attention output
  short* kms = Xb + 4194304;            // 8 KB sigma64 bf16 key-mask frags

  prep<<<3600,256,0,stream>>>(K, V, Wo, key_mask, Ktw, Vtw, Wb, kms);
  attn11<<<512,256,0,stream>>>(Ktw, Vtw, Q, kms, query_mask, Xb);
  proj5<<<256,512,0,stream>>>(Xb, Wb, bo, (float*)d_out);
}